// Round 5
// baseline (894.167 us; speedup 1.0000x reference)
//
#include <hip/hip_runtime.h>
#include <math.h>

#define N_CLASSES 18
#define NMS_PRE   1000
#define K_NMS     500
#define POOL      4000      // 4 * NMS_PRE
#define LIST_CAP  2048
#define IOU_THR   0.5f
#define SCORE_THR 0.01f

typedef unsigned long long ull;

struct Ptrs {
  const float* cent[4];
  const float* bbox[4];
  const float* cls[4];
  const float* pts[4];
  int off[4];
  int ntot;
};

__device__ __forceinline__ unsigned int fsort(float f){
  unsigned int b = __float_as_uint(f);
  return (b & 0x80000000u) ? ~b : (b | 0x80000000u);
}
__device__ __forceinline__ float fsort_inv(unsigned int k){
  unsigned int b = (k & 0x80000000u) ? (k & 0x7FFFFFFFu) : ~k;
  return __uint_as_float(b);
}
__device__ __forceinline__ float sigmoidf_(float x){
  return 1.0f / (1.0f + expf(-x));
}
__device__ __forceinline__ int level_of(int f, const Ptrs& P){
  return (f >= P.off[3]) ? 3 : (f >= P.off[2]) ? 2 : (f >= P.off[1]) ? 1 : 0;
}

// compare-exchange helpers for hybrid bitonic (desc).
__device__ __forceinline__ ull cx_keep(ull mine, ull part, bool keep_hi){
  ull mx = mine > part ? mine : part;
  ull mn = mine > part ? part : mine;
  return keep_hi ? mx : mn;
}
__device__ __forceinline__ void cxpair(ull &a, ull &b, bool a_hi){
  ull mx = a > b ? a : b;
  ull mn = a > b ? b : a;
  a = a_hi ? mx : mn;
  b = a_hi ? mn : mx;
}

// Descending cumulative scan over 2048 bins of level w; finds threshold bin.
// st: LDS 4*2048 counts. pass0: krem=NMS_PRE, Pfx=0, state <- b<<21.
// pass1: krem/Pfx from state, state <- Pfx | (b<<10).
__device__ __forceinline__ void level_scan(const unsigned int* st, unsigned int* state,
                                           int pass, int w, int lane){
  unsigned int krem = (pass == 0) ? (unsigned)NMS_PRE : state[2*w + 1];
  unsigned int Pfx  = (pass == 0) ? 0u : state[2*w];
  unsigned int carry = 0;
  for (int ch = 0; ch < 32; ++ch){
    unsigned int cnt = st[w*2048 + 2047 - (ch*64 + lane)];
    unsigned int pfx = cnt;
#pragma unroll
    for (int off2 = 1; off2 < 64; off2 <<= 1){
      unsigned int u = __shfl_up(pfx, off2);
      if (lane >= off2) pfx += u;
    }
    unsigned int C = carry + pfx;
    ull bal = __ballot(C >= krem);
    if (bal){
      int fl2 = __ffsll(bal) - 1;
      unsigned int Cf = __shfl(C, fl2);
      unsigned int cf = __shfl(cnt, fl2);
      if (lane == 0){
        unsigned int b = (unsigned int)(2047 - (ch*64 + fl2));
        state[2*w]     = (pass == 0) ? (b << 21) : (Pfx | (b << 10));
        state[2*w + 1] = krem - (Cf - cf);
      }
      return;
    }
    carry = __shfl(C, 63);
  }
}

// ---------------- stage 1: keys + pass-0 histogram + last-block scan0 -------
__global__ void __launch_bounds__(512) compute_keys(Ptrs P, unsigned int* keys,
                        unsigned int* hist, unsigned int* state, unsigned int* done){
  extern __shared__ char smem[];
  float* cls_s = (float*)smem;                    // 512*18 f32 = 36864 B
  unsigned int* lh = (unsigned int*)(smem + 36864); // 2048 u32 = 8192 B
  int t = threadIdx.x;
  int f0 = blockIdx.x << 9;
  int f = f0 + t;
  for (int j = t; j < 2048; j += 512) lh[j] = 0u;
  bool valid = f < P.ntot;
  int fl = min(f0 + 511, P.ntot - 1);
  bool uni = (level_of(f0, P) == level_of(fl, P)) && (f0 + 511 < P.ntot);
  int Lb = level_of(f0, P);
  float m = 0.f, cent = 0.f;
  if (uni){
    const float4* base4 = (const float4*)(P.cls[Lb] + (size_t)(f0 - P.off[Lb]) * N_CLASSES);
    cent = P.cent[Lb][f - P.off[Lb]];             // prefetch before barrier
    for (int j = t; j < 2304; j += 512) ((float4*)cls_s)[j] = base4[j];
    __syncthreads();
    m = cls_s[t*18];
#pragma unroll
    for (int c2 = 1; c2 < N_CLASSES; ++c2) m = fmaxf(m, cls_s[t*18 + c2]);
  } else {
    __syncthreads();
    if (valid){
      int L = level_of(f, P); int i = f - P.off[L];
      const float* cl = P.cls[L] + (size_t)i * N_CLASSES;
      m = cl[0];
      for (int c2 = 1; c2 < N_CLASSES; ++c2) m = fmaxf(m, cl[c2]);
      cent = P.cent[L][i];
    }
  }
  if (valid){
    // sigmoid monotone => sig(max)*sig(cent) == max_c(sig(c)*sig(cent))
    float s = sigmoidf_(m) * sigmoidf_(cent);
    unsigned int key = fsort(s);
    keys[f] = key;
    if (uni) atomicAdd(&lh[key >> 21], 1u);
    else     atomicAdd(&hist[level_of(f, P)*2048 + (key >> 21)], 1u);
  }
  __syncthreads();
  if (uni){
    for (int j = t; j < 2048; j += 512){
      unsigned int v = lh[j];
      if (v) atomicAdd(&hist[Lb*2048 + j], v);
    }
  }
  // -------- last block: scan pass 0 (atomic reads for cross-XCD coherence) --
  __threadfence();
  __shared__ unsigned int lastS;
  if (t == 0) lastS = (atomicAdd(done, 1u) == gridDim.x - 1) ? 1u : 0u;
  __syncthreads();
  if (!lastS) return;
  unsigned int* st = (unsigned int*)smem;         // reuse cls_s region (32 KB)
  for (int j = t; j < 8192; j += 512) st[j] = atomicAdd(&hist[j], 0u);
  __syncthreads();
  if (t < 256) level_scan(st, state, 0, t >> 6, t & 63);
  __syncthreads();
  for (int j = t; j < 8192; j += 512) hist[j] = 0u;  // ready for pass 1
}

// ---------------- stage 2: pass-1 histogram + last-block scan1 --------------
__global__ void __launch_bounds__(256) hist1_scan(Ptrs P, const unsigned int* keys,
                        unsigned int* state, unsigned int* hist, unsigned int* done2){
  int t = threadIdx.x;
  int f = blockIdx.x * 256 + t;
  if (f < P.ntot){
    int L = level_of(f, P);
    unsigned int key = keys[f];
    unsigned int Pfx = state[2*L];
    if ((key >> 21) == (Pfx >> 21))
      atomicAdd(&hist[L*2048 + ((key >> 10) & 0x7FFu)], 1u);
  }
  __threadfence();
  __shared__ unsigned int lastS;
  if (t == 0) lastS = (atomicAdd(done2, 1u) == gridDim.x - 1) ? 1u : 0u;
  __syncthreads();
  if (!lastS) return;
  __shared__ unsigned int st[8192];
  for (int j = t; j < 8192; j += 256) st[j] = atomicAdd(&hist[j], 0u);
  __syncthreads();
  level_scan(st, state, 1, t >> 6, t & 63);
}

// ---------------- stage 3: compact keys >= T (22-bit-prefix lower bound) ----
__global__ void __launch_bounds__(256) compact_kernel(Ptrs P, const unsigned int* keys,
                        const unsigned int* state, unsigned int* cnts, ull* lists){
  int f = blockIdx.x * 256 + threadIdx.x;
  if (f >= P.ntot) return;
  int L = level_of(f, P);
  unsigned int key = keys[f];
  unsigned int T = state[2*L];
  if (key >= T){
    unsigned int pos = atomicAdd(&cnts[L], 1u);
    if (pos < LIST_CAP){
      unsigned int i = (unsigned int)(f - P.off[L]);
      lists[(size_t)L*LIST_CAP + pos] = ((ull)key << 32) | (ull)(~i);
    }
  }
}

// ---------------- stage 4: hybrid bitonic sort + fused gather/decode --------
__global__ void __launch_bounds__(1024) sort_gather(Ptrs P, const ull* lists,
                        const unsigned int* cnts, float* boxes_pool, float* scores_pool){
  __shared__ ull buf[LIST_CAP];
  int L = blockIdx.x;
  int t = threadIdx.x;
  unsigned int cnt = cnts[L]; if (cnt > LIST_CAP) cnt = LIST_CAP;
  const ull* src = lists + (size_t)L*LIST_CAP;
  ull v0 = 0ull;
  if (cnt <= 1024u){
    v0 = (t < (int)cnt) ? src[t] : 0ull;
    for (int k = 2; k <= 1024; k <<= 1){
      for (int j = k >> 1; j > 0; j >>= 1){
        bool hi0 = (((t & j) == 0) == ((t & k) == 0));
        if (j >= 64){
          __syncthreads();
          buf[t] = v0;
          __syncthreads();
          v0 = cx_keep(v0, buf[t ^ j], hi0);
        } else {
          v0 = cx_keep(v0, __shfl_xor(v0, j), hi0);
        }
      }
    }
  } else {
    int e1 = t + 1024;
    v0      = (t  < (int)cnt) ? src[t]  : 0ull;
    ull v1  = (e1 < (int)cnt) ? src[e1] : 0ull;
    for (int k = 2; k <= 2048; k <<= 1){
      for (int j = k >> 1; j > 0; j >>= 1){
        bool hi0 = (((t  & j) == 0) == ((t  & k) == 0));
        bool hi1 = (((e1 & j) == 0) == ((e1 & k) == 0));
        if (j >= 1024){
          cxpair(v0, v1, hi0);
        } else if (j >= 64){
          __syncthreads();
          buf[t] = v0; buf[e1] = v1;
          __syncthreads();
          ull p0 = buf[t ^ j];
          ull p1 = buf[e1 ^ j];
          v0 = cx_keep(v0, p0, hi0);
          v1 = cx_keep(v1, p1, hi1);
        } else {
          v0 = cx_keep(v0, __shfl_xor(v0, j), hi0);
          v1 = cx_keep(v1, __shfl_xor(v1, j), hi1);
        }
      }
    }
  }
  if (t < NMS_PRE){
    unsigned int i = ~((unsigned int)(v0 & 0xFFFFFFFFu));
    const float* bp = P.bbox[L] + (size_t)i * 6;
    const float* pp = P.pts[L]  + (size_t)i * 3;
    float p0 = bp[0], p1 = bp[1], p2 = bp[2], p3 = bp[3], p4 = bp[4], p5 = bp[5];
    float cx = pp[0] + (p1 - p0) * 0.5f;
    float cy = pp[1] + (p3 - p2) * 0.5f;
    float cz = pp[2] + (p5 - p4) * 0.5f;
    float w = p0 + p1, l = p2 + p3, h = p4 + p5;
    int r = L * NMS_PRE + t;
    float* bo = boxes_pool + (size_t)r * 6;
    bo[0] = cx; bo[1] = cy; bo[2] = cz; bo[3] = w; bo[4] = l; bo[5] = h;
    float cs = sigmoidf_(P.cent[L][i]);
    const float* cl = P.cls[L] + (size_t)i * N_CLASSES;
#pragma unroll
    for (int c = 0; c < N_CLASSES; ++c)
      scores_pool[(size_t)c * POOL + r] = sigmoidf_(cl[c]) * cs;
  }
}

// ---------------- stage 5: per-class topk + mask + greedy, all in one block -
__global__ void __launch_bounds__(1024) class_all(const float* scores_pool,
                        const float* boxes_pool, float* out){
  __shared__ unsigned int keyS[4096];
  __shared__ ull comp[512];
  __shared__ unsigned int histS[256];
  __shared__ unsigned int wsum[16], wpre[16];
  __shared__ unsigned int sP, sK, sCnt;
  __shared__ float smn0[512], smn1[512], smn2[512];
  __shared__ float smx0[512], smx1[512], smx2[512];
  __shared__ float svol[512];
  __shared__ ull maskS[K_NMS*8];
  __shared__ ull flagRow[8], vbitsS[8], remS[8];
  int c = blockIdx.x;
  int t = threadIdx.x;
  int w = t >> 6, lane = t & 63;

  for (int j = t; j < 4096; j += 1024){
    unsigned int k = 0u;
    if (j < POOL){
      float s = scores_pool[(size_t)c*POOL + j];
      float sval = (s > SCORE_THR) ? s : -1.0f;
      k = fsort(sval);
    }
    keyS[j] = k;
  }
  if (t == 0){ sP = 0u; sK = K_NMS; sCnt = 0u; }
  if (t < 8) flagRow[t] = 0ull;
  __syncthreads();

  // exact 500th-largest key via 4x8-bit radix select
  for (int pass = 0; pass < 4; ++pass){
    int shift = 24 - 8*pass;
    if (t < 256) histS[t] = 0u;
    __syncthreads();
    unsigned int Pfx = sP;
    for (int j = t; j < 4096; j += 1024){
      unsigned int k = keyS[j];
      if ((((ull)(k ^ Pfx)) >> (shift + 8)) == 0ull)
        atomicAdd(&histS[(k >> shift) & 0xFFu], 1u);
    }
    __syncthreads();
    if (w == 0){
      unsigned int krem = sK;
      unsigned int carry = 0;
      for (int ch = 0; ch < 4; ++ch){
        unsigned int cnt = histS[255 - (ch*64 + lane)];
        unsigned int pfx = cnt;
#pragma unroll
        for (int off = 1; off < 64; off <<= 1){
          unsigned int u = __shfl_up(pfx, off);
          if (lane >= off) pfx += u;
        }
        unsigned int C = carry + pfx;
        ull bal = __ballot(C >= krem);
        if (bal){
          int fl = __ffsll(bal) - 1;
          unsigned int Cf = __shfl(C, fl);
          unsigned int cf = __shfl(cnt, fl);
          if (lane == 0){
            sP = Pfx | ((unsigned int)(255 - (ch*64 + fl)) << shift);
            sK = krem - (Cf - cf);
          }
          break;
        }
        carry = __shfl(C, 63);
      }
    }
    __syncthreads();
  }
  unsigned int T = sP, need = sK;

  // ordered tie rank via block prefix scan; thread t owns keyS[4t..4t+4)
  unsigned int loc[4]; unsigned int ct = 0;
#pragma unroll
  for (int q = 0; q < 4; ++q){
    unsigned int k = keyS[4*t + q];
    loc[q] = k;
    ct += (k == T) ? 1u : 0u;
  }
  unsigned int inc = ct;
#pragma unroll
  for (int off = 1; off < 64; off <<= 1){
    unsigned int u = __shfl_up(inc, off);
    if (lane >= off) inc += u;
  }
  if (lane == 63) wsum[w] = inc;
  __syncthreads();
  if (t < 16){
    unsigned int v = wsum[t];
    unsigned int pincl = v;
#pragma unroll
    for (int off = 1; off < 16; off <<= 1){
      unsigned int u = __shfl_up(pincl, off);
      if (t >= off) pincl += u;
    }
    wpre[t] = pincl - v;
  }
  __syncthreads();
  unsigned int excl = wpre[w] + (inc - ct);

#pragma unroll
  for (int q = 0; q < 4; ++q){
    unsigned int k = loc[q];
    bool surv = false;
    if (k > T) surv = true;
    else if (k == T){ surv = (excl < need); excl += 1u; }
    if (surv){
      unsigned int pos = atomicAdd(&sCnt, 1u);
      if (pos < 512)
        comp[pos] = ((ull)k << 32) | (ull)(~(unsigned int)(4*t + q));
    }
  }
  __syncthreads();

  // hybrid bitonic desc over 512 (threads t<512 own elem t)
  ull v0 = 0ull;
  if (t < 512 && t < (int)sCnt) v0 = comp[t];
  for (int k = 2; k <= 512; k <<= 1){
    for (int j = k >> 1; j > 0; j >>= 1){
      if (j >= 64){
        __syncthreads();
        if (t < 512) comp[t] = v0;
        __syncthreads();
        if (t < 512){
          bool hi0 = (((t & j) == 0) == ((t & k) == 0));
          v0 = cx_keep(v0, comp[t ^ j], hi0);
        }
      } else {
        if (t < 512){
          bool hi0 = (((t & j) == 0) == ((t & k) == 0));
          v0 = cx_keep(v0, __shfl_xor(v0, j), hi0);
        }
      }
    }
  }

  // epilogue: outputs + AABB into LDS
  float sval = -1.0f;
  if (t < 512){
    sval = fsort_inv((unsigned int)(v0 >> 32));
    smn0[t] = 0.f; smn1[t] = 0.f; smn2[t] = 0.f;
    smx0[t] = 0.f; smx1[t] = 0.f; smx2[t] = 0.f; svol[t] = 0.f;
  }
  if (t < K_NMS){
    unsigned int j = ~((unsigned int)(v0 & 0xFFFFFFFFu));
    int o = c*K_NMS + t;
    const float* bp = boxes_pool + (size_t)j * 6;
    float b0 = bp[0], b1 = bp[1], b2 = bp[2], b3 = bp[3], b4 = bp[4], b5 = bp[5];
    float* ob = out + (size_t)o * 6;
    ob[0] = b0; ob[1] = b1; ob[2] = b2; ob[3] = b3; ob[4] = b4; ob[5] = b5;
    out[54000 + o] = sval;
    out[63000 + o] = (float)c;
    float mn0 = b0 - b3*0.5f, mx0 = b0 + b3*0.5f;
    float mn1 = b1 - b4*0.5f, mx1 = b1 + b4*0.5f;
    float mn2 = b2 - b5*0.5f, mx2 = b2 + b5*0.5f;
    smn0[t] = mn0; smn1[t] = mn1; smn2[t] = mn2;
    smx0[t] = mx0; smx1[t] = mx1; smx2[t] = mx2;
    svol[t] = fmaxf(mx0 - mn0, 0.f) * fmaxf(mx1 - mn1, 0.f) * fmaxf(mx2 - mn2, 0.f);
  }
  ull vb = __ballot(sval > SCORE_THR);
  if (w < 8 && lane == 0) vbitsS[w] = vb;
  __syncthreads();

  // mask build: group A (t<512) even rows, group B (t>=512) odd rows
  int tc = t & 511;
  int gw = w & 7;
  float cmn0 = smn0[tc], cmn1 = smn1[tc], cmn2 = smn2[tc];
  float cmx0 = smx0[tc], cmx1 = smx1[tc], cmx2 = smx2[tc];
  float cvol = svol[tc];
  for (int it = 0; it < 250; ++it){
    int i = 2*it + (t >= 512 ? 1 : 0);
    float lt0 = fmaxf(smn0[i], cmn0), lt1 = fmaxf(smn1[i], cmn1), lt2 = fmaxf(smn2[i], cmn2);
    float rb0 = fminf(smx0[i], cmx0), rb1 = fminf(smx1[i], cmx1), rb2 = fminf(smx2[i], cmx2);
    float inter = fmaxf(rb0 - lt0, 0.f) * fmaxf(rb1 - lt1, 0.f) * fmaxf(rb2 - lt2, 0.f);
    float denom = svol[i] + cvol - inter + 1e-6f;
    bool s = (tc < K_NMS) && (tc > i) && (inter / denom > IOU_THR);
    ull m = __ballot(s);
    if (lane == 0){
      maskS[i*8 + gw] = m;
      if (m) atomicOr(&flagRow[i >> 6], 1ull << (i & 63));
    }
  }
  __syncthreads();

  // greedy (wave 0): replicated 512-bit bitset + event skipping
  if (w == 0){
    ull rem[8];
#pragma unroll
    for (int q = 0; q < 8; ++q) rem[q] = ~vbitsS[q];   // sup0 = !valid
#pragma unroll
    for (int q = 0; q < 8; ++q){
      ull fq = flagRow[q];
      ull cand = fq & ~rem[q];
      while (cand){
        int b = __ffsll(cand) - 1;
        int i = q*64 + b;
#pragma unroll
        for (int z = 0; z < 8; ++z) rem[z] |= maskS[i*8 + z];
        ull above = (b < 63) ? (~0ull << (b + 1)) : 0ull;
        cand = fq & ~rem[q] & above;                   // masks only set bits > i
      }
    }
    if (lane == 0){
#pragma unroll
      for (int q = 0; q < 8; ++q) remS[q] = rem[q];
    }
  }
  __syncthreads();
  if (t < K_NMS)
    out[72000 + c*K_NMS + t] = ((remS[t >> 6] >> (t & 63)) & 1ull) ? 0.0f : 1.0f;
}

// ---------------------------------------------------------------------------
extern "C" void kernel_launch(void* const* d_in, const int* in_sizes, int n_in,
                              void* d_out, int out_size, void* d_ws, size_t ws_size,
                              hipStream_t stream){
  Ptrs P;
  int off = 0;
  for (int L = 0; L < 4; ++L){
    P.cent[L] = (const float*)d_in[4*L + 0];
    P.bbox[L] = (const float*)d_in[4*L + 1];
    P.cls[L]  = (const float*)d_in[4*L + 2];
    P.pts[L]  = (const float*)d_in[4*L + 3];
    P.off[L]  = off;
    off += in_sizes[4*L + 0];
  }
  P.ntot = off;

  char* w = (char*)d_ws;
  size_t o = 0;
  auto alloc = [&](size_t bytes) -> char* {
    char* p = w + o;
    o = (o + bytes + 255) & ~(size_t)255;
    return p;
  };
  unsigned int* keys  = (unsigned int*)alloc((size_t)P.ntot * 4);
  // contiguous zeroed ctrl block: hist(32KB) | cnts(16B) | done(4) | done2(4)
  char* ctrl          = alloc(32768 + 16 + 4 + 4);
  unsigned int* hist  = (unsigned int*)ctrl;
  unsigned int* cnts  = (unsigned int*)(ctrl + 32768);
  unsigned int* done  = (unsigned int*)(ctrl + 32784);
  unsigned int* done2 = (unsigned int*)(ctrl + 32788);
  unsigned int* state = (unsigned int*)alloc(4 * 2 * 4);   // written before read
  ull* lists          = (ull*)alloc((size_t)4 * LIST_CAP * 8);
  float* boxes_pool   = (float*)alloc((size_t)POOL * 6 * 4);
  float* scores_pool  = (float*)alloc((size_t)N_CLASSES * POOL * 4);

  float* out = (float*)d_out;
  int grid512 = (P.ntot + 511) / 512;
  int grid256 = (P.ntot + 255) / 256;

  hipMemsetAsync(ctrl, 0, 32768 + 24, stream);
  compute_keys<<<grid512, 512, 45056, stream>>>(P, keys, hist, state, done);
  hist1_scan<<<grid256, 256, 0, stream>>>(P, keys, state, hist, done2);
  compact_kernel<<<grid256, 256, 0, stream>>>(P, keys, state, cnts, lists);
  sort_gather<<<4, 1024, 0, stream>>>(P, lists, cnts, boxes_pool, scores_pool);
  class_all<<<N_CLASSES, 1024, 0, stream>>>(scores_pool, boxes_pool, out);
}

// Round 6
// 359.736 us; speedup vs baseline: 2.4856x; 2.4856x over previous
//
#include <hip/hip_runtime.h>
#include <math.h>

#define N_CLASSES 18
#define NMS_PRE   1000
#define K_NMS     500
#define POOL      4000      // 4 * NMS_PRE
#define LIST_CAP  2048
#define IOU_THR   0.5f
#define SCORE_THR 0.01f

typedef unsigned long long ull;

struct Ptrs {
  const float* cent[4];
  const float* bbox[4];
  const float* cls[4];
  const float* pts[4];
  int off[4];
  int ntot;
};

__device__ __forceinline__ unsigned int fsort(float f){
  unsigned int b = __float_as_uint(f);
  return (b & 0x80000000u) ? ~b : (b | 0x80000000u);
}
__device__ __forceinline__ float fsort_inv(unsigned int k){
  unsigned int b = (k & 0x80000000u) ? (k & 0x7FFFFFFFu) : ~k;
  return __uint_as_float(b);
}
__device__ __forceinline__ float sigmoidf_(float x){
  return 1.0f / (1.0f + expf(-x));
}
__device__ __forceinline__ int level_of(int f, const Ptrs& P){
  return (f >= P.off[3]) ? 3 : (f >= P.off[2]) ? 2 : (f >= P.off[1]) ? 1 : 0;
}

// compare-exchange helpers for hybrid bitonic (desc).
__device__ __forceinline__ ull cx_keep(ull mine, ull part, bool keep_hi){
  ull mx = mine > part ? mine : part;
  ull mn = mine > part ? part : mine;
  return keep_hi ? mx : mn;
}
__device__ __forceinline__ void cxpair(ull &a, ull &b, bool a_hi){
  ull mx = a > b ? a : b;
  ull mn = a > b ? b : a;
  a = a_hi ? mx : mn;
  b = a_hi ? mn : mx;
}

// Descending cumulative scan over 2048 bins of level w; finds threshold bin.
__device__ __forceinline__ void level_scan(const unsigned int* st, unsigned int* state,
                                           int pass, int w, int lane){
  unsigned int krem = (pass == 0) ? (unsigned)NMS_PRE : state[2*w + 1];
  unsigned int Pfx  = (pass == 0) ? 0u : state[2*w];
  unsigned int carry = 0;
  for (int ch = 0; ch < 32; ++ch){
    unsigned int cnt = st[w*2048 + 2047 - (ch*64 + lane)];
    unsigned int pfx = cnt;
#pragma unroll
    for (int off2 = 1; off2 < 64; off2 <<= 1){
      unsigned int u = __shfl_up(pfx, off2);
      if (lane >= off2) pfx += u;
    }
    unsigned int C = carry + pfx;
    ull bal = __ballot(C >= krem);
    if (bal){
      int fl2 = __ffsll(bal) - 1;
      unsigned int Cf = __shfl(C, fl2);
      unsigned int cf = __shfl(cnt, fl2);
      if (lane == 0){
        unsigned int b = (unsigned int)(2047 - (ch*64 + fl2));
        state[2*w]     = (pass == 0) ? (b << 21) : (Pfx | (b << 10));
        state[2*w + 1] = krem - (Cf - cf);
      }
      return;
    }
    carry = __shfl(C, 63);
  }
}

// ---------------- stage 1: keys + pass-0 histogram (no fences!) -------------
__global__ void __launch_bounds__(512) compute_keys(Ptrs P, unsigned int* keys,
                        unsigned int* hist){
  __shared__ float cls_s[512*18];       // 36864 B, linear staging
  __shared__ unsigned int lh[2048];     // 8192 B
  int t = threadIdx.x;
  int f0 = blockIdx.x << 9;
  int f = f0 + t;
  for (int j = t; j < 2048; j += 512) lh[j] = 0u;
  bool valid = f < P.ntot;
  int fl = min(f0 + 511, P.ntot - 1);
  bool uni = (level_of(f0, P) == level_of(fl, P)) && (f0 + 511 < P.ntot);
  int Lb = level_of(f0, P);
  float m = 0.f, cent = 0.f;
  if (uni){
    const float4* base4 = (const float4*)(P.cls[Lb] + (size_t)(f0 - P.off[Lb]) * N_CLASSES);
    cent = P.cent[Lb][f - P.off[Lb]];   // prefetch before barrier
    for (int j = t; j < 2304; j += 512) ((float4*)cls_s)[j] = base4[j];
    __syncthreads();
    m = cls_s[t*18];
#pragma unroll
    for (int c2 = 1; c2 < N_CLASSES; ++c2) m = fmaxf(m, cls_s[t*18 + c2]);
  } else {
    __syncthreads();
    if (valid){
      int L = level_of(f, P); int i = f - P.off[L];
      const float* cl = P.cls[L] + (size_t)i * N_CLASSES;
      m = cl[0];
      for (int c2 = 1; c2 < N_CLASSES; ++c2) m = fmaxf(m, cl[c2]);
      cent = P.cent[L][i];
    }
  }
  if (valid){
    // sigmoid monotone => sig(max)*sig(cent) == max_c(sig(c)*sig(cent))
    float s = sigmoidf_(m) * sigmoidf_(cent);
    unsigned int key = fsort(s);
    keys[f] = key;
    if (uni) atomicAdd(&lh[key >> 21], 1u);
    else     atomicAdd(&hist[level_of(f, P)*2048 + (key >> 21)], 1u);
  }
  __syncthreads();
  if (uni){
    for (int j = t; j < 2048; j += 512){
      unsigned int v = lh[j];
      if (v) atomicAdd(&hist[Lb*2048 + j], v);
    }
  }
}

// ---------------- stage 2: 1-block scan (pass 0 or 1) -----------------------
__global__ void __launch_bounds__(256) scan_level(unsigned int* hist, unsigned int* state,
                        int pass){
  __shared__ unsigned int st[8192];
  int t = threadIdx.x;
  for (int j = t; j < 8192; j += 256) st[j] = hist[j];
  __syncthreads();
  level_scan(st, state, pass, t >> 6, t & 63);
  if (pass == 0){
    __syncthreads();
    for (int j = t; j < 8192; j += 256) hist[j] = 0u;   // ready for pass 1
  }
}

// ---------------- stage 3: second 11-bit histogram pass ---------------------
__global__ void __launch_bounds__(256) hist1(Ptrs P, const unsigned int* keys,
                        const unsigned int* state, unsigned int* hist){
  int f = blockIdx.x * 256 + threadIdx.x;
  if (f < P.ntot){
    int L = level_of(f, P);
    unsigned int key = keys[f];
    unsigned int Pfx = state[2*L];
    if ((key >> 21) == (Pfx >> 21))
      atomicAdd(&hist[L*2048 + ((key >> 10) & 0x7FFu)], 1u);
  }
}

// ---------------- stage 4: compact keys >= T (22-bit-prefix lower bound) ----
__global__ void __launch_bounds__(256) compact_kernel(Ptrs P, const unsigned int* keys,
                        const unsigned int* state, unsigned int* cnts, ull* lists){
  int f = blockIdx.x * 256 + threadIdx.x;
  if (f >= P.ntot) return;
  int L = level_of(f, P);
  unsigned int key = keys[f];
  unsigned int T = state[2*L];
  if (key >= T){
    unsigned int pos = atomicAdd(&cnts[L], 1u);
    if (pos < LIST_CAP){
      unsigned int i = (unsigned int)(f - P.off[L]);
      lists[(size_t)L*LIST_CAP + pos] = ((ull)key << 32) | (ull)(~i);
    }
  }
}

// ---------------- stage 5: hybrid bitonic sort + fused gather/decode --------
__global__ void __launch_bounds__(1024) sort_gather(Ptrs P, const ull* lists,
                        const unsigned int* cnts, float* boxes_pool, float* scores_pool){
  __shared__ ull buf[LIST_CAP];
  int L = blockIdx.x;
  int t = threadIdx.x;
  unsigned int cnt = cnts[L]; if (cnt > LIST_CAP) cnt = LIST_CAP;
  const ull* src = lists + (size_t)L*LIST_CAP;
  ull v0 = 0ull;
  if (cnt <= 1024u){
    v0 = (t < (int)cnt) ? src[t] : 0ull;
    for (int k = 2; k <= 1024; k <<= 1){
      for (int j = k >> 1; j > 0; j >>= 1){
        bool hi0 = (((t & j) == 0) == ((t & k) == 0));
        if (j >= 64){
          __syncthreads();
          buf[t] = v0;
          __syncthreads();
          v0 = cx_keep(v0, buf[t ^ j], hi0);
        } else {
          v0 = cx_keep(v0, __shfl_xor(v0, j), hi0);
        }
      }
    }
  } else {
    int e1 = t + 1024;
    v0      = (t  < (int)cnt) ? src[t]  : 0ull;
    ull v1  = (e1 < (int)cnt) ? src[e1] : 0ull;
    for (int k = 2; k <= 2048; k <<= 1){
      for (int j = k >> 1; j > 0; j >>= 1){
        bool hi0 = (((t  & j) == 0) == ((t  & k) == 0));
        bool hi1 = (((e1 & j) == 0) == ((e1 & k) == 0));
        if (j >= 1024){
          cxpair(v0, v1, hi0);
        } else if (j >= 64){
          __syncthreads();
          buf[t] = v0; buf[e1] = v1;
          __syncthreads();
          ull p0 = buf[t ^ j];
          ull p1 = buf[e1 ^ j];
          v0 = cx_keep(v0, p0, hi0);
          v1 = cx_keep(v1, p1, hi1);
        } else {
          v0 = cx_keep(v0, __shfl_xor(v0, j), hi0);
          v1 = cx_keep(v1, __shfl_xor(v1, j), hi1);
        }
      }
    }
  }
  if (t < NMS_PRE){
    unsigned int i = ~((unsigned int)(v0 & 0xFFFFFFFFu));
    const float* bp = P.bbox[L] + (size_t)i * 6;
    const float* pp = P.pts[L]  + (size_t)i * 3;
    float p0 = bp[0], p1 = bp[1], p2 = bp[2], p3 = bp[3], p4 = bp[4], p5 = bp[5];
    float cx = pp[0] + (p1 - p0) * 0.5f;
    float cy = pp[1] + (p3 - p2) * 0.5f;
    float cz = pp[2] + (p5 - p4) * 0.5f;
    float w = p0 + p1, l = p2 + p3, h = p4 + p5;
    int r = L * NMS_PRE + t;
    float* bo = boxes_pool + (size_t)r * 6;
    bo[0] = cx; bo[1] = cy; bo[2] = cz; bo[3] = w; bo[4] = l; bo[5] = h;
    float cs = sigmoidf_(P.cent[L][i]);
    const float* cl = P.cls[L] + (size_t)i * N_CLASSES;
#pragma unroll
    for (int c = 0; c < N_CLASSES; ++c)
      scores_pool[(size_t)c * POOL + r] = sigmoidf_(cl[c]) * cs;
  }
}

// ---------------- stage 6: per-class topk + mask + greedy, one block/class --
__global__ void __launch_bounds__(1024) class_all(const float* scores_pool,
                        const float* boxes_pool, float* out){
  __shared__ unsigned int keyS[4096];
  __shared__ ull comp[512];
  __shared__ unsigned int histS[256];
  __shared__ unsigned int wsum[16], wpre[16];
  __shared__ unsigned int sP, sK, sCnt;
  __shared__ float smn0[512], smn1[512], smn2[512];
  __shared__ float smx0[512], smx1[512], smx2[512];
  __shared__ float svol[512];
  __shared__ ull maskS[K_NMS*8];
  __shared__ ull flagRow[8], vbitsS[8], remS[8];
  int c = blockIdx.x;
  int t = threadIdx.x;
  int w = t >> 6, lane = t & 63;

  for (int j = t; j < 4096; j += 1024){
    unsigned int k = 0u;
    if (j < POOL){
      float s = scores_pool[(size_t)c*POOL + j];
      float sval = (s > SCORE_THR) ? s : -1.0f;
      k = fsort(sval);
    }
    keyS[j] = k;
  }
  if (t == 0){ sP = 0u; sK = K_NMS; sCnt = 0u; }
  if (t < 8) flagRow[t] = 0ull;
  __syncthreads();

  // exact 500th-largest key via 4x8-bit radix select
  for (int pass = 0; pass < 4; ++pass){
    int shift = 24 - 8*pass;
    if (t < 256) histS[t] = 0u;
    __syncthreads();
    unsigned int Pfx = sP;
    for (int j = t; j < 4096; j += 1024){
      unsigned int k = keyS[j];
      if ((((ull)(k ^ Pfx)) >> (shift + 8)) == 0ull)
        atomicAdd(&histS[(k >> shift) & 0xFFu], 1u);
    }
    __syncthreads();
    if (w == 0){
      unsigned int krem = sK;
      unsigned int carry = 0;
      for (int ch = 0; ch < 4; ++ch){
        unsigned int cnt = histS[255 - (ch*64 + lane)];
        unsigned int pfx = cnt;
#pragma unroll
        for (int off = 1; off < 64; off <<= 1){
          unsigned int u = __shfl_up(pfx, off);
          if (lane >= off) pfx += u;
        }
        unsigned int C = carry + pfx;
        ull bal = __ballot(C >= krem);
        if (bal){
          int fl = __ffsll(bal) - 1;
          unsigned int Cf = __shfl(C, fl);
          unsigned int cf = __shfl(cnt, fl);
          if (lane == 0){
            sP = Pfx | ((unsigned int)(255 - (ch*64 + fl)) << shift);
            sK = krem - (Cf - cf);
          }
          break;
        }
        carry = __shfl(C, 63);
      }
    }
    __syncthreads();
  }
  unsigned int T = sP, need = sK;

  // ordered tie rank via block prefix scan; thread t owns keyS[4t..4t+4)
  unsigned int loc[4]; unsigned int ct = 0;
#pragma unroll
  for (int q = 0; q < 4; ++q){
    unsigned int k = keyS[4*t + q];
    loc[q] = k;
    ct += (k == T) ? 1u : 0u;
  }
  unsigned int inc = ct;
#pragma unroll
  for (int off = 1; off < 64; off <<= 1){
    unsigned int u = __shfl_up(inc, off);
    if (lane >= off) inc += u;
  }
  if (lane == 63) wsum[w] = inc;
  __syncthreads();
  if (t < 16){
    unsigned int v = wsum[t];
    unsigned int pincl = v;
#pragma unroll
    for (int off = 1; off < 16; off <<= 1){
      unsigned int u = __shfl_up(pincl, off);
      if (t >= off) pincl += u;
    }
    wpre[t] = pincl - v;
  }
  __syncthreads();
  unsigned int excl = wpre[w] + (inc - ct);

#pragma unroll
  for (int q = 0; q < 4; ++q){
    unsigned int k = loc[q];
    bool surv = false;
    if (k > T) surv = true;
    else if (k == T){ surv = (excl < need); excl += 1u; }
    if (surv){
      unsigned int pos = atomicAdd(&sCnt, 1u);
      if (pos < 512)
        comp[pos] = ((ull)k << 32) | (ull)(~(unsigned int)(4*t + q));
    }
  }
  __syncthreads();

  // hybrid bitonic desc over 512 (threads t<512 own elem t)
  ull v0 = 0ull;
  if (t < 512 && t < (int)sCnt) v0 = comp[t];
  for (int k = 2; k <= 512; k <<= 1){
    for (int j = k >> 1; j > 0; j >>= 1){
      if (j >= 64){
        __syncthreads();
        if (t < 512) comp[t] = v0;
        __syncthreads();
        if (t < 512){
          bool hi0 = (((t & j) == 0) == ((t & k) == 0));
          v0 = cx_keep(v0, comp[t ^ j], hi0);
        }
      } else {
        if (t < 512){
          bool hi0 = (((t & j) == 0) == ((t & k) == 0));
          v0 = cx_keep(v0, __shfl_xor(v0, j), hi0);
        }
      }
    }
  }

  // epilogue: outputs + AABB into LDS
  float sval = -1.0f;
  if (t < 512){
    sval = fsort_inv((unsigned int)(v0 >> 32));
    smn0[t] = 0.f; smn1[t] = 0.f; smn2[t] = 0.f;
    smx0[t] = 0.f; smx1[t] = 0.f; smx2[t] = 0.f; svol[t] = 0.f;
  }
  if (t < K_NMS){
    unsigned int j = ~((unsigned int)(v0 & 0xFFFFFFFFu));
    int o = c*K_NMS + t;
    const float* bp = boxes_pool + (size_t)j * 6;
    float b0 = bp[0], b1 = bp[1], b2 = bp[2], b3 = bp[3], b4 = bp[4], b5 = bp[5];
    float* ob = out + (size_t)o * 6;
    ob[0] = b0; ob[1] = b1; ob[2] = b2; ob[3] = b3; ob[4] = b4; ob[5] = b5;
    out[54000 + o] = sval;
    out[63000 + o] = (float)c;
    float mn0 = b0 - b3*0.5f, mx0 = b0 + b3*0.5f;
    float mn1 = b1 - b4*0.5f, mx1 = b1 + b4*0.5f;
    float mn2 = b2 - b5*0.5f, mx2 = b2 + b5*0.5f;
    smn0[t] = mn0; smn1[t] = mn1; smn2[t] = mn2;
    smx0[t] = mx0; smx1[t] = mx1; smx2[t] = mx2;
    svol[t] = fmaxf(mx0 - mn0, 0.f) * fmaxf(mx1 - mn1, 0.f) * fmaxf(mx2 - mn2, 0.f);
  }
  ull vb = __ballot(sval > SCORE_THR);
  if (w < 8 && lane == 0) vbitsS[w] = vb;
  __syncthreads();

  // mask build: group A (t<512) even rows, group B (t>=512) odd rows
  int tc = t & 511;
  int gw = w & 7;
  float cmn0 = smn0[tc], cmn1 = smn1[tc], cmn2 = smn2[tc];
  float cmx0 = smx0[tc], cmx1 = smx1[tc], cmx2 = smx2[tc];
  float cvol = svol[tc];
  for (int it = 0; it < 250; ++it){
    int i = 2*it + (t >= 512 ? 1 : 0);
    float lt0 = fmaxf(smn0[i], cmn0), lt1 = fmaxf(smn1[i], cmn1), lt2 = fmaxf(smn2[i], cmn2);
    float rb0 = fminf(smx0[i], cmx0), rb1 = fminf(smx1[i], cmx1), rb2 = fminf(smx2[i], cmx2);
    float inter = fmaxf(rb0 - lt0, 0.f) * fmaxf(rb1 - lt1, 0.f) * fmaxf(rb2 - lt2, 0.f);
    float denom = svol[i] + cvol - inter + 1e-6f;
    bool s = (tc < K_NMS) && (tc > i) && (inter / denom > IOU_THR);
    ull m = __ballot(s);
    if (lane == 0){
      maskS[i*8 + gw] = m;
      if (m) atomicOr(&flagRow[i >> 6], 1ull << (i & 63));
    }
  }
  __syncthreads();

  // greedy (wave 0): replicated 512-bit bitset + event skipping
  if (w == 0){
    ull rem[8];
#pragma unroll
    for (int q = 0; q < 8; ++q) rem[q] = ~vbitsS[q];   // sup0 = !valid
#pragma unroll
    for (int q = 0; q < 8; ++q){
      ull fq = flagRow[q];
      ull cand = fq & ~rem[q];
      while (cand){
        int b = __ffsll(cand) - 1;
        int i = q*64 + b;
#pragma unroll
        for (int z = 0; z < 8; ++z) rem[z] |= maskS[i*8 + z];
        ull above = (b < 63) ? (~0ull << (b + 1)) : 0ull;
        cand = fq & ~rem[q] & above;                   // masks only set bits > i
      }
    }
    if (lane == 0){
#pragma unroll
      for (int q = 0; q < 8; ++q) remS[q] = rem[q];
    }
  }
  __syncthreads();
  if (t < K_NMS)
    out[72000 + c*K_NMS + t] = ((remS[t >> 6] >> (t & 63)) & 1ull) ? 0.0f : 1.0f;
}

// ---------------------------------------------------------------------------
extern "C" void kernel_launch(void* const* d_in, const int* in_sizes, int n_in,
                              void* d_out, int out_size, void* d_ws, size_t ws_size,
                              hipStream_t stream){
  Ptrs P;
  int off = 0;
  for (int L = 0; L < 4; ++L){
    P.cent[L] = (const float*)d_in[4*L + 0];
    P.bbox[L] = (const float*)d_in[4*L + 1];
    P.cls[L]  = (const float*)d_in[4*L + 2];
    P.pts[L]  = (const float*)d_in[4*L + 3];
    P.off[L]  = off;
    off += in_sizes[4*L + 0];
  }
  P.ntot = off;

  char* w = (char*)d_ws;
  size_t o = 0;
  auto alloc = [&](size_t bytes) -> char* {
    char* p = w + o;
    o = (o + bytes + 255) & ~(size_t)255;
    return p;
  };
  unsigned int* keys  = (unsigned int*)alloc((size_t)P.ntot * 4);
  // contiguous zeroed ctrl block: hist(32KB) | cnts(16B)
  char* ctrl          = alloc(32768 + 16);
  unsigned int* hist  = (unsigned int*)ctrl;
  unsigned int* cnts  = (unsigned int*)(ctrl + 32768);
  unsigned int* state = (unsigned int*)alloc(4 * 2 * 4);   // written before read
  ull* lists          = (ull*)alloc((size_t)4 * LIST_CAP * 8);
  float* boxes_pool   = (float*)alloc((size_t)POOL * 6 * 4);
  float* scores_pool  = (float*)alloc((size_t)N_CLASSES * POOL * 4);

  float* out = (float*)d_out;
  int grid512 = (P.ntot + 511) / 512;
  int grid256 = (P.ntot + 255) / 256;

  hipMemsetAsync(ctrl, 0, 32768 + 16, stream);
  compute_keys<<<grid512, 512, 0, stream>>>(P, keys, hist);
  scan_level<<<1, 256, 0, stream>>>(hist, state, 0);
  hist1<<<grid256, 256, 0, stream>>>(P, keys, state, hist);
  scan_level<<<1, 256, 0, stream>>>(hist, state, 1);
  compact_kernel<<<grid256, 256, 0, stream>>>(P, keys, state, cnts, lists);
  sort_gather<<<4, 1024, 0, stream>>>(P, lists, cnts, boxes_pool, scores_pool);
  class_all<<<N_CLASSES, 1024, 0, stream>>>(scores_pool, boxes_pool, out);
}

// Round 7
// 332.272 us; speedup vs baseline: 2.6911x; 1.0827x over previous
//
#include <hip/hip_runtime.h>
#include <math.h>

#define N_CLASSES 18
#define NMS_PRE   1000
#define K_NMS     500
#define POOL      4000      // 4 * NMS_PRE
#define LIST_CAP  2048
#define IOU_THR   0.5f
#define SCORE_THR 0.01f

typedef unsigned long long ull;

struct Ptrs {
  const float* cent[4];
  const float* bbox[4];
  const float* cls[4];
  const float* pts[4];
  int off[4];
  int ntot;
};

__device__ __forceinline__ unsigned int fsort(float f){
  unsigned int b = __float_as_uint(f);
  return (b & 0x80000000u) ? ~b : (b | 0x80000000u);
}
__device__ __forceinline__ float fsort_inv(unsigned int k){
  unsigned int b = (k & 0x80000000u) ? (k & 0x7FFFFFFFu) : ~k;
  return __uint_as_float(b);
}
__device__ __forceinline__ float sigmoidf_(float x){
  return 1.0f / (1.0f + expf(-x));
}
__device__ __forceinline__ int level_of(int f, const Ptrs& P){
  return (f >= P.off[3]) ? 3 : (f >= P.off[2]) ? 2 : (f >= P.off[1]) ? 1 : 0;
}

// compare-exchange helpers for hybrid bitonic (desc).
__device__ __forceinline__ ull cx_keep(ull mine, ull part, bool keep_hi){
  ull mx = mine > part ? mine : part;
  ull mn = mine > part ? part : mine;
  return keep_hi ? mx : mn;
}
__device__ __forceinline__ void cxpair(ull &a, ull &b, bool a_hi){
  ull mx = a > b ? a : b;
  ull mn = a > b ? b : a;
  a = a_hi ? mx : mn;
  b = a_hi ? mn : mx;
}

// Descending cumulative scan over 2048 bins of level w; finds threshold bin.
__device__ __forceinline__ void level_scan(const unsigned int* st, unsigned int* state,
                                           int pass, int w, int lane){
  unsigned int krem = (pass == 0) ? (unsigned)NMS_PRE : state[2*w + 1];
  unsigned int Pfx  = (pass == 0) ? 0u : state[2*w];
  unsigned int carry = 0;
  for (int ch = 0; ch < 32; ++ch){
    unsigned int cnt = st[w*2048 + 2047 - (ch*64 + lane)];
    unsigned int pfx = cnt;
#pragma unroll
    for (int off2 = 1; off2 < 64; off2 <<= 1){
      unsigned int u = __shfl_up(pfx, off2);
      if (lane >= off2) pfx += u;
    }
    unsigned int C = carry + pfx;
    ull bal = __ballot(C >= krem);
    if (bal){
      int fl2 = __ffsll(bal) - 1;
      unsigned int Cf = __shfl(C, fl2);
      unsigned int cf = __shfl(cnt, fl2);
      if (lane == 0){
        unsigned int b = (unsigned int)(2047 - (ch*64 + fl2));
        state[2*w]     = (pass == 0) ? (b << 21) : (Pfx | (b << 10));
        state[2*w + 1] = krem - (Cf - cf);
      }
      return;
    }
    carry = __shfl(C, 63);
  }
}

__device__ __forceinline__ float max4(float4 v){
  return fmaxf(fmaxf(v.x, v.y), fmaxf(v.z, v.w));
}

// ---------------- stage 1: keys (2 pts/thread, registers) + hist0 + scan0 ---
// Cross-block sync WITHOUT threadfence: all global hist updates use RETURNING
// device-scope atomics (response => performed at global coherence point),
// then the done-counter; last block re-reads hist with atomic loads.
__global__ void __launch_bounds__(256) compute_keys(Ptrs P, unsigned int* keys,
                        unsigned int* hist, unsigned int* state, unsigned int* done,
                        int nblocks){
  __shared__ unsigned int sbuf[8192];   // [0..2047] = block hist; later reused for scan
  __shared__ unsigned int lastS;
  int t = threadIdx.x;
  int f0 = blockIdx.x << 9;             // 512 points per block
  for (int j = t; j < 2048; j += 256) sbuf[j] = 0u;
  __syncthreads();
  int fl = min(f0 + 511, P.ntot - 1);
  bool uni = (level_of(f0, P) == level_of(fl, P)) && (f0 + 511 < P.ntot);
  unsigned int acc = 0;
  if (uni){
    int L = level_of(f0, P);
    size_t ib = (size_t)(f0 - P.off[L]);
    const float4* base4 = (const float4*)(P.cls[L] + ib * N_CLASSES);
    float4 v0 = base4[9*t+0], v1 = base4[9*t+1], v2 = base4[9*t+2];
    float4 v3 = base4[9*t+3], v4 = base4[9*t+4], v5 = base4[9*t+5];
    float4 v6 = base4[9*t+6], v7 = base4[9*t+7], v8 = base4[9*t+8];
    float2 cc = *(const float2*)(P.cent[L] + ib + 2*t);
    float m0 = fmaxf(fmaxf(max4(v0), max4(v1)), fmaxf(max4(v2), max4(v3)));
    m0 = fmaxf(m0, fmaxf(v4.x, v4.y));
    float m1 = fmaxf(fmaxf(max4(v5), max4(v6)), fmaxf(max4(v7), max4(v8)));
    m1 = fmaxf(m1, fmaxf(v4.z, v4.w));
    // sigmoid monotone => sig(max)*sig(cent) == max_c(sig(c)*sig(cent))
    float s0 = sigmoidf_(m0) * sigmoidf_(cc.x);
    float s1 = sigmoidf_(m1) * sigmoidf_(cc.y);
    unsigned int k0 = fsort(s0), k1 = fsort(s1);
    *(uint2*)(keys + f0 + 2*t) = make_uint2(k0, k1);
    atomicAdd(&sbuf[k0 >> 21], 1u);     // LDS: no return needed (barrier below)
    atomicAdd(&sbuf[k1 >> 21], 1u);
  } else {
#pragma unroll
    for (int q = 0; q < 2; ++q){
      int f = f0 + 2*t + q;
      if (f < P.ntot){
        int L = level_of(f, P); int i = f - P.off[L];
        const float* cl = P.cls[L] + (size_t)i * N_CLASSES;
        float m = cl[0];
        for (int c2 = 1; c2 < N_CLASSES; ++c2) m = fmaxf(m, cl[c2]);
        float s = sigmoidf_(m) * sigmoidf_(P.cent[L][i]);
        unsigned int k = fsort(s);
        keys[f] = k;
        acc += atomicAdd(&hist[L*2048 + (k >> 21)], 1u);  // returning
      }
    }
  }
  __syncthreads();
  if (uni){
    int L = level_of(f0, P);
    for (int j = t; j < 2048; j += 256){
      unsigned int vv = sbuf[j];
      if (vv) acc += atomicAdd(&hist[L*2048 + j], vv);    // returning
    }
  }
  __asm__ volatile("" :: "v"(acc));     // force vmcnt wait: atomics performed
  __syncthreads();
  if (t == 0) lastS = (atomicAdd(done, 1u) == (unsigned)(nblocks - 1)) ? 1u : 0u;
  __syncthreads();
  if (!lastS) return;
  // ---- last block: scan pass 0 (atomic reads see all performed atomics) ----
  for (int j = t; j < 8192; j += 256) sbuf[j] = atomicAdd(&hist[j], 0u);
  __syncthreads();
  level_scan(sbuf, state, 0, t >> 6, t & 63);
  __syncthreads();
  for (int j = t; j < 8192; j += 256) hist[j] = 0u;  // ready for pass 1
}

// ---------------- stage 2: pass-1 histogram + fused scan1 -------------------
__global__ void __launch_bounds__(1024) hist1(Ptrs P, const unsigned int* keys,
                        unsigned int* state, unsigned int* hist, unsigned int* done2,
                        int nblocks){
  __shared__ unsigned int st[8192];
  __shared__ unsigned int lastS;
  int t = threadIdx.x;
  int f = blockIdx.x * 1024 + t;
  unsigned int acc = 0;
  if (f < P.ntot){
    int L = level_of(f, P);
    unsigned int key = keys[f];
    unsigned int Pfx = state[2*L];
    if ((key >> 21) == (Pfx >> 21))
      acc = atomicAdd(&hist[L*2048 + ((key >> 10) & 0x7FFu)], 1u);  // returning
  }
  __asm__ volatile("" :: "v"(acc));
  __syncthreads();
  if (t == 0) lastS = (atomicAdd(done2, 1u) == (unsigned)(nblocks - 1)) ? 1u : 0u;
  __syncthreads();
  if (!lastS) return;
  for (int j = t; j < 8192; j += 1024) st[j] = atomicAdd(&hist[j], 0u);
  __syncthreads();
  if (t < 256) level_scan(st, state, 1, t >> 6, t & 63);
}

// ---------------- stage 3: compact keys >= T (22-bit-prefix lower bound) ----
__global__ void __launch_bounds__(256) compact_kernel(Ptrs P, const unsigned int* keys,
                        const unsigned int* state, unsigned int* cnts, ull* lists){
  int f = blockIdx.x * 256 + threadIdx.x;
  if (f >= P.ntot) return;
  int L = level_of(f, P);
  unsigned int key = keys[f];
  unsigned int T = state[2*L];
  if (key >= T){
    unsigned int pos = atomicAdd(&cnts[L], 1u);
    if (pos < LIST_CAP){
      unsigned int i = (unsigned int)(f - P.off[L]);
      lists[(size_t)L*LIST_CAP + pos] = ((ull)key << 32) | (ull)(~i);
    }
  }
}

// ---------------- stage 4: hybrid bitonic sort + fused gather/decode --------
__global__ void __launch_bounds__(1024) sort_gather(Ptrs P, const ull* lists,
                        const unsigned int* cnts, float* boxes_pool, float* scores_pool){
  __shared__ ull buf[LIST_CAP];
  int L = blockIdx.x;
  int t = threadIdx.x;
  unsigned int cnt = cnts[L]; if (cnt > LIST_CAP) cnt = LIST_CAP;
  const ull* src = lists + (size_t)L*LIST_CAP;
  ull v0 = 0ull;
  if (cnt <= 1024u){
    v0 = (t < (int)cnt) ? src[t] : 0ull;
    for (int k = 2; k <= 1024; k <<= 1){
      for (int j = k >> 1; j > 0; j >>= 1){
        bool hi0 = (((t & j) == 0) == ((t & k) == 0));
        if (j >= 64){
          __syncthreads();
          buf[t] = v0;
          __syncthreads();
          v0 = cx_keep(v0, buf[t ^ j], hi0);
        } else {
          v0 = cx_keep(v0, __shfl_xor(v0, j), hi0);
        }
      }
    }
  } else {
    int e1 = t + 1024;
    v0      = (t  < (int)cnt) ? src[t]  : 0ull;
    ull v1  = (e1 < (int)cnt) ? src[e1] : 0ull;
    for (int k = 2; k <= 2048; k <<= 1){
      for (int j = k >> 1; j > 0; j >>= 1){
        bool hi0 = (((t  & j) == 0) == ((t  & k) == 0));
        bool hi1 = (((e1 & j) == 0) == ((e1 & k) == 0));
        if (j >= 1024){
          cxpair(v0, v1, hi0);
        } else if (j >= 64){
          __syncthreads();
          buf[t] = v0; buf[e1] = v1;
          __syncthreads();
          ull p0 = buf[t ^ j];
          ull p1 = buf[e1 ^ j];
          v0 = cx_keep(v0, p0, hi0);
          v1 = cx_keep(v1, p1, hi1);
        } else {
          v0 = cx_keep(v0, __shfl_xor(v0, j), hi0);
          v1 = cx_keep(v1, __shfl_xor(v1, j), hi1);
        }
      }
    }
  }
  if (t < NMS_PRE){
    unsigned int i = ~((unsigned int)(v0 & 0xFFFFFFFFu));
    const float* bp = P.bbox[L] + (size_t)i * 6;
    const float* pp = P.pts[L]  + (size_t)i * 3;
    float p0 = bp[0], p1 = bp[1], p2 = bp[2], p3 = bp[3], p4 = bp[4], p5 = bp[5];
    float cx = pp[0] + (p1 - p0) * 0.5f;
    float cy = pp[1] + (p3 - p2) * 0.5f;
    float cz = pp[2] + (p5 - p4) * 0.5f;
    float w = p0 + p1, l = p2 + p3, h = p4 + p5;
    int r = L * NMS_PRE + t;
    float* bo = boxes_pool + (size_t)r * 6;
    bo[0] = cx; bo[1] = cy; bo[2] = cz; bo[3] = w; bo[4] = l; bo[5] = h;
    float cs = sigmoidf_(P.cent[L][i]);
    const float* cl = P.cls[L] + (size_t)i * N_CLASSES;
#pragma unroll
    for (int c = 0; c < N_CLASSES; ++c)
      scores_pool[(size_t)c * POOL + r] = sigmoidf_(cl[c]) * cs;
  }
}

// ---------------- stage 5: per-class exact top-500 (radix select + sort512) -
__global__ void __launch_bounds__(1024) class_topk(const float* scores_pool,
                        const float* boxes_pool, float* out, float* aabb){
  __shared__ unsigned int keyS[4096];
  __shared__ ull comp[512];
  __shared__ unsigned int histS[256];
  __shared__ unsigned int wsum[16], wpre[16];
  __shared__ unsigned int sP, sK, sCnt;
  int c = blockIdx.x;
  int t = threadIdx.x;
  int w = t >> 6, lane = t & 63;

  for (int j = t; j < 4096; j += 1024){
    unsigned int k = 0u;
    if (j < POOL){
      float s = scores_pool[(size_t)c*POOL + j];
      float sval = (s > SCORE_THR) ? s : -1.0f;
      k = fsort(sval);
    }
    keyS[j] = k;
  }
  if (t == 0){ sP = 0u; sK = K_NMS; sCnt = 0u; }
  __syncthreads();

  for (int pass = 0; pass < 4; ++pass){
    int shift = 24 - 8*pass;
    if (t < 256) histS[t] = 0u;
    __syncthreads();
    unsigned int Pfx = sP;
    for (int j = t; j < 4096; j += 1024){
      unsigned int k = keyS[j];
      if ((((ull)(k ^ Pfx)) >> (shift + 8)) == 0ull)
        atomicAdd(&histS[(k >> shift) & 0xFFu], 1u);
    }
    __syncthreads();
    if (w == 0){
      unsigned int krem = sK;
      unsigned int carry = 0;
      for (int ch = 0; ch < 4; ++ch){
        unsigned int cnt = histS[255 - (ch*64 + lane)];
        unsigned int pfx = cnt;
#pragma unroll
        for (int off = 1; off < 64; off <<= 1){
          unsigned int u = __shfl_up(pfx, off);
          if (lane >= off) pfx += u;
        }
        unsigned int C = carry + pfx;
        ull bal = __ballot(C >= krem);
        if (bal){
          int fl = __ffsll(bal) - 1;
          unsigned int Cf = __shfl(C, fl);
          unsigned int cf = __shfl(cnt, fl);
          if (lane == 0){
            sP = Pfx | ((unsigned int)(255 - (ch*64 + fl)) << shift);
            sK = krem - (Cf - cf);
          }
          break;
        }
        carry = __shfl(C, 63);
      }
    }
    __syncthreads();
  }
  unsigned int T = sP, need = sK;

  unsigned int loc[4]; unsigned int ct = 0;
#pragma unroll
  for (int q = 0; q < 4; ++q){
    unsigned int k = keyS[4*t + q];
    loc[q] = k;
    ct += (k == T) ? 1u : 0u;
  }
  unsigned int inc = ct;
#pragma unroll
  for (int off = 1; off < 64; off <<= 1){
    unsigned int u = __shfl_up(inc, off);
    if (lane >= off) inc += u;
  }
  if (lane == 63) wsum[w] = inc;
  __syncthreads();
  if (t < 16){
    unsigned int v = wsum[t];
    unsigned int pincl = v;
#pragma unroll
    for (int off = 1; off < 16; off <<= 1){
      unsigned int u = __shfl_up(pincl, off);
      if (t >= off) pincl += u;
    }
    wpre[t] = pincl - v;
  }
  __syncthreads();
  unsigned int excl = wpre[w] + (inc - ct);

#pragma unroll
  for (int q = 0; q < 4; ++q){
    unsigned int k = loc[q];
    bool surv = false;
    if (k > T) surv = true;
    else if (k == T){ surv = (excl < need); excl += 1u; }
    if (surv){
      unsigned int pos = atomicAdd(&sCnt, 1u);
      if (pos < 512)
        comp[pos] = ((ull)k << 32) | (ull)(~(unsigned int)(4*t + q));
    }
  }
  __syncthreads();

  // hybrid bitonic desc over 512 (threads t<512 own elem t)
  ull v0 = 0ull;
  if (t < 512 && t < (int)sCnt) v0 = comp[t];
  for (int k = 2; k <= 512; k <<= 1){
    for (int j = k >> 1; j > 0; j >>= 1){
      if (j >= 64){
        __syncthreads();
        if (t < 512) comp[t] = v0;
        __syncthreads();
        if (t < 512){
          bool hi0 = (((t & j) == 0) == ((t & k) == 0));
          v0 = cx_keep(v0, comp[t ^ j], hi0);
        }
      } else {
        if (t < 512){
          bool hi0 = (((t & j) == 0) == ((t & k) == 0));
          v0 = cx_keep(v0, __shfl_xor(v0, j), hi0);
        }
      }
    }
  }

  if (t < K_NMS){
    ull cm = v0;
    unsigned int j = ~((unsigned int)(cm & 0xFFFFFFFFu));
    float sval = fsort_inv((unsigned int)(cm >> 32));
    int o = c*K_NMS + t;
    const float* bp = boxes_pool + (size_t)j * 6;
    float b0 = bp[0], b1 = bp[1], b2 = bp[2], b3 = bp[3], b4 = bp[4], b5 = bp[5];
    float* ob = out + (size_t)o * 6;
    ob[0] = b0; ob[1] = b1; ob[2] = b2; ob[3] = b3; ob[4] = b4; ob[5] = b5;
    out[54000 + o] = sval;
    out[63000 + o] = (float)c;
    float mn0 = b0 - b3*0.5f, mx0 = b0 + b3*0.5f;
    float mn1 = b1 - b4*0.5f, mx1 = b1 + b4*0.5f;
    float mn2 = b2 - b5*0.5f, mx2 = b2 + b5*0.5f;
    float vol = fmaxf(mx0 - mn0, 0.f) * fmaxf(mx1 - mn1, 0.f) * fmaxf(mx2 - mn2, 0.f);
    float* ap = aabb + ((size_t)c*512 + t) * 8;
    ap[0] = mn0; ap[1] = mn1; ap[2] = mn2; ap[3] = mx0; ap[4] = mx1; ap[5] = mx2;
    ap[6] = vol; ap[7] = sval;
  }
}

// ---------------- stage 6a: NMS mask build + per-row nonzero flags ----------
__global__ void __launch_bounds__(512) nms_mask(const float* aabb, ull* maskG, ull* flagsG){
  __shared__ float smn0[512], smn1[512], smn2[512];
  __shared__ float smx0[512], smx1[512], smx2[512];
  __shared__ float svol[512];
  __shared__ ull rowbuf[64*8];
  int c = blockIdx.y, chunk = blockIdx.x;
  int t = threadIdx.x, w = t >> 6, lane = t & 63;
  float mn0 = 0.f, mn1 = 0.f, mn2 = 0.f, mx0 = 0.f, mx1 = 0.f, mx2 = 0.f, vol = 0.f;
  if (t < K_NMS){
    const float* ap = aabb + ((size_t)c*512 + t) * 8;
    mn0 = ap[0]; mn1 = ap[1]; mn2 = ap[2];
    mx0 = ap[3]; mx1 = ap[4]; mx2 = ap[5]; vol = ap[6];
  }
  smn0[t] = mn0; smn1[t] = mn1; smn2[t] = mn2;
  smx0[t] = mx0; smx1[t] = mx1; smx2[t] = mx2;
  svol[t] = vol;
  __syncthreads();
  int i0 = chunk * 64, i1 = min(i0 + 64, K_NMS);
  for (int i = i0; i < i1; ++i){
    float lt0 = fmaxf(smn0[i], mn0), lt1 = fmaxf(smn1[i], mn1), lt2 = fmaxf(smn2[i], mn2);
    float rb0 = fminf(smx0[i], mx0), rb1 = fminf(smx1[i], mx1), rb2 = fminf(smx2[i], mx2);
    float inter = fmaxf(rb0 - lt0, 0.f) * fmaxf(rb1 - lt1, 0.f) * fmaxf(rb2 - lt2, 0.f);
    float denom = svol[i] + vol - inter + 1e-6f;
    bool s = (t < K_NMS) && (t > i) && (inter / denom > IOU_THR);
    ull m = __ballot(s);
    if (lane == 0){
      maskG[((size_t)c*K_NMS + i)*8 + w] = m;
      rowbuf[(i - i0)*8 + w] = m;
    }
  }
  __syncthreads();
  if (t < 64){
    int r = i0 + t;
    bool nz = false;
    if (r < K_NMS){
      ull o = 0ull;
#pragma unroll
      for (int z = 0; z < 8; ++z) o |= rowbuf[t*8 + z];
      nz = (o != 0ull);
    }
    ull bal = __ballot(nz);
    if (t == 0) flagsG[(size_t)c*8 + chunk] = bal;
  }
}

// ---------------- stage 6b: greedy — replicated bitset + event skipping -----
__global__ void __launch_bounds__(512) nms_greedy(const float* aabb, const ull* maskG,
                        const ull* flagsG, float* keep_out){
  __shared__ ull maskS[K_NMS*8];
  __shared__ ull vbitsS[8], remS[8];
  int c = blockIdx.x, t = threadIdx.x, w = t >> 6, lane = t & 63;
  ull flg[8];
#pragma unroll
  for (int q = 0; q < 8; ++q) flg[q] = flagsG[(size_t)c*8 + q];
  for (int j = t; j < K_NMS*8; j += 512) maskS[j] = maskG[(size_t)c*K_NMS*8 + j];
  float sv = (t < K_NMS) ? aabb[((size_t)c*512 + t)*8 + 7] : -1.0f;
  ull vb = __ballot(sv > SCORE_THR);
  if (lane == 0) vbitsS[w] = vb;
  __syncthreads();
  if (w == 0){
    ull rem[8];
#pragma unroll
    for (int q = 0; q < 8; ++q) rem[q] = ~vbitsS[q];   // sup0 = !valid
#pragma unroll
    for (int q = 0; q < 8; ++q){
      ull fq = flg[q];
      ull cand = fq & ~rem[q];
      while (cand){
        int b = __ffsll(cand) - 1;
        int i = q*64 + b;
#pragma unroll
        for (int z = 0; z < 8; ++z) rem[z] |= maskS[i*8 + z];
        ull above = (b < 63) ? (~0ull << (b + 1)) : 0ull;
        cand = fq & ~rem[q] & above;                   // masks only set bits > i
      }
    }
    if (lane == 0){
#pragma unroll
      for (int q = 0; q < 8; ++q) remS[q] = rem[q];
    }
  }
  __syncthreads();
  if (t < K_NMS)
    keep_out[c*K_NMS + t] = ((remS[t >> 6] >> (t & 63)) & 1ull) ? 0.0f : 1.0f;
}

// ---------------------------------------------------------------------------
extern "C" void kernel_launch(void* const* d_in, const int* in_sizes, int n_in,
                              void* d_out, int out_size, void* d_ws, size_t ws_size,
                              hipStream_t stream){
  Ptrs P;
  int off = 0;
  for (int L = 0; L < 4; ++L){
    P.cent[L] = (const float*)d_in[4*L + 0];
    P.bbox[L] = (const float*)d_in[4*L + 1];
    P.cls[L]  = (const float*)d_in[4*L + 2];
    P.pts[L]  = (const float*)d_in[4*L + 3];
    P.off[L]  = off;
    off += in_sizes[4*L + 0];
  }
  P.ntot = off;

  char* w = (char*)d_ws;
  size_t o = 0;
  auto alloc = [&](size_t bytes) -> char* {
    char* p = w + o;
    o = (o + bytes + 255) & ~(size_t)255;
    return p;
  };
  unsigned int* keys  = (unsigned int*)alloc((size_t)P.ntot * 4);
  // contiguous zeroed ctrl block: hist(32KB) | cnts(16B) | done(4) | done2(4)
  char* ctrl          = alloc(32768 + 24);
  unsigned int* hist  = (unsigned int*)ctrl;
  unsigned int* cnts  = (unsigned int*)(ctrl + 32768);
  unsigned int* done  = (unsigned int*)(ctrl + 32784);
  unsigned int* done2 = (unsigned int*)(ctrl + 32788);
  unsigned int* state = (unsigned int*)alloc(4 * 2 * 4);   // written before read
  ull* lists          = (ull*)alloc((size_t)4 * LIST_CAP * 8);
  float* boxes_pool   = (float*)alloc((size_t)POOL * 6 * 4);
  float* scores_pool  = (float*)alloc((size_t)N_CLASSES * POOL * 4);
  float* aabb         = (float*)alloc((size_t)N_CLASSES * 512 * 8 * 4);
  ull* maskG          = (ull*)alloc((size_t)N_CLASSES * K_NMS * 8 * 8);
  ull* flagsG         = (ull*)alloc((size_t)N_CLASSES * 8 * 8);

  float* out = (float*)d_out;
  int grid512  = (P.ntot + 511) / 512;
  int grid256  = (P.ntot + 255) / 256;
  int grid1024 = (P.ntot + 1023) / 1024;

  hipMemsetAsync(ctrl, 0, 32768 + 24, stream);
  compute_keys<<<grid512, 256, 0, stream>>>(P, keys, hist, state, done, grid512);
  hist1<<<grid1024, 1024, 0, stream>>>(P, keys, state, hist, done2, grid1024);
  compact_kernel<<<grid256, 256, 0, stream>>>(P, keys, state, cnts, lists);
  sort_gather<<<4, 1024, 0, stream>>>(P, lists, cnts, boxes_pool, scores_pool);
  class_topk<<<N_CLASSES, 1024, 0, stream>>>(scores_pool, boxes_pool, out, aabb);
  nms_mask<<<dim3(8, N_CLASSES), 512, 0, stream>>>(aabb, maskG, flagsG);
  nms_greedy<<<N_CLASSES, 512, 0, stream>>>(aabb, maskG, flagsG, out + 72000);
}